// Round 1
// 480.677 us; speedup vs baseline: 1.4568x; 1.4568x over previous
//
#include <hip/hip_runtime.h>

typedef __attribute__((ext_vector_type(8))) short short8;
typedef __attribute__((ext_vector_type(4))) float floatx4;

static constexpr int D = 1024;
static constexpr int F = 2048;
static constexpr int E = 8;
static constexpr int TOK = 4 * 2048;   // 8192 tokens
static constexpr int RTOT = 2 * TOK;   // 16384 expert-rows total (top-2 exact)
static constexpr int MT = 24;          // m-tiles per expert (3072 rows >> mean 2048)
static constexpr int RBLK = 512;       // router blocks (16 tokens each)

__device__ __forceinline__ unsigned short f2bf(float f) {
  unsigned int u = __float_as_uint(f);
  unsigned int r = (u + 0x7fffu + ((u >> 16) & 1u)) >> 16;  // RNE
  return (unsigned short)r;
}

__device__ __forceinline__ void glds16(const unsigned short* g, unsigned short* l) {
  __builtin_amdgcn_global_load_lds(
      (const __attribute__((address_space(1))) void*)g,
      (__attribute__((address_space(3))) void*)l, 16, 0, 0);
}

// meta layout (ints): [0:8)=cntp  [8:16)=cnts  [16:24)=pbase  [24:32)=sbase
//                     [32:40)=curp [40:48)=curs
// ---------------- router (+ fused X fp32->bf16 convert) ----------------
// 512 blocks x 256 thr. Wave = 1 token at a time (4 per wave).
// rw staged transposed in LDS once per block; butterfly reduce; LDS histogram;
// per-block counts written NON-atomically to blkcnt (prefix_kernel sums them).
__global__ __launch_bounds__(256) void router_kernel(
    const float* __restrict__ hs, const int* __restrict__ mask,
    const float* __restrict__ rw, int2* __restrict__ te, float2* __restrict__ tw,
    int* __restrict__ blkcnt, unsigned short* __restrict__ Xbf) {
  __shared__ float rwT[E][D];    // 32 KB, transposed [e][i]
  __shared__ int cnt[16];
  int tid = threadIdx.x;
  if (tid < 16) cnt[tid] = 0;
  // stage rw ([D][E] fp32) transposed into LDS
#pragma unroll
  for (int q = 0; q < 4; ++q) {
    int i = tid * 4 + q;
    float4 a = *(const float4*)(rw + (size_t)i * E);
    float4 b = *(const float4*)(rw + (size_t)i * E + 4);
    rwT[0][i] = a.x; rwT[1][i] = a.y; rwT[2][i] = a.z; rwT[3][i] = a.w;
    rwT[4][i] = b.x; rwT[5][i] = b.y; rwT[6][i] = b.z; rwT[7][i] = b.w;
  }
  __syncthreads();

  int lane = tid & 63, wid = tid >> 6;
  int tok0 = blockIdx.x * 16 + wid * 4;
#pragma unroll 1
  for (int tt = 0; tt < 4; ++tt) {
    int t = tok0 + tt;
    const float* x = hs + (size_t)t * D;
    float acc[E];
#pragma unroll
    for (int e = 0; e < E; ++e) acc[e] = 0.f;
#pragma unroll
    for (int j = 0; j < 4; ++j) {
      int i0 = j * 256 + lane * 4;
      float4 xv = *(const float4*)(x + i0);
      // fused bf16 convert+store of X (replaces cvt_kernel)
      union { unsigned short u[4]; uint2 q; } p;
      p.u[0] = f2bf(xv.x); p.u[1] = f2bf(xv.y);
      p.u[2] = f2bf(xv.z); p.u[3] = f2bf(xv.w);
      *(uint2*)(Xbf + (size_t)t * D + i0) = p.q;
#pragma unroll
      for (int e = 0; e < E; ++e) {
        float4 rv = *(const float4*)&rwT[e][i0];   // 16B/lane stride: conflict-free
        acc[e] += xv.x * rv.x + xv.y * rv.y + xv.z * rv.z + xv.w * rv.w;
      }
    }
    // butterfly reduce across 64 lanes (all lanes end with full sums)
#pragma unroll
    for (int off = 32; off > 0; off >>= 1) {
#pragma unroll
      for (int e = 0; e < E; ++e) acc[e] += __shfl_xor(acc[e], off, 64);
    }
    if (lane == 0) {
      int i1 = 0;
#pragma unroll
      for (int e = 1; e < E; ++e) if (acc[e] > acc[i1]) i1 = e;  // lowest argmax (jax tie rule)
      int i2 = (i1 == 0) ? 1 : 0;
#pragma unroll
      for (int e = 0; e < E; ++e) if (e != i1 && acc[e] > acc[i2]) i2 = e;
      float mx = fmaxf(acc[i1], acc[i2]);
      float e1 = expf(acc[i1] - mx), e2 = expf(acc[i2] - mx);
      float s = e1 + e2;
      float m = (mask[t] != 0) ? 1.f : 0.f;
      te[t] = make_int2(i1, i2);
      tw[t] = make_float2(e1 / s * m, e2 / s * m);
      atomicAdd(&cnt[i1], 1);       // LDS histogram — no global contention
      atomicAdd(&cnt[8 + i2], 1);
    }
  }
  __syncthreads();
  if (tid < 16) blkcnt[blockIdx.x * 16 + tid] = cnt[tid];
}

// ---------------- prefix: sum per-block histograms + exclusive scan ----------------
__global__ __launch_bounds__(256) void prefix_kernel(const int* __restrict__ blkcnt,
                                                     int* __restrict__ meta) {
  __shared__ int part[256];
  int tid = threadIdx.x;
  int c = tid & 15, g = tid >> 4;   // 16 threads per counter, each sums 32 blocks
  int s = 0;
  for (int b = g; b < RBLK; b += 16) s += blkcnt[b * 16 + c];
  part[tid] = s;
  __syncthreads();
  if (tid < 16) {
    int tot = 0;
#pragma unroll
    for (int g2 = 0; g2 < 16; ++g2) tot += part[g2 * 16 + tid];
    meta[tid] = tot;
  }
  __syncthreads();
  if (tid == 0) {
    int run = 0;
    for (int e = 0; e < E; ++e) {
      meta[16 + e] = run;                 // pbase
      meta[24 + e] = run + meta[e];       // sbase
      run += meta[e] + meta[8 + e];
    }
  }
}

// ---------------- scatter: build LIST/WTS (wave-aggregated atomics) ----------------
__global__ __launch_bounds__(256) void scatter_kernel(
    const int2* __restrict__ te, const float2* __restrict__ tw,
    int* __restrict__ meta, int* __restrict__ LIST, float* __restrict__ WTS) {
  int t = blockIdx.x * 256 + threadIdx.x;
  int lane = threadIdx.x & 63;
  int2 e = te[t];
  float2 w = tw[t];
#pragma unroll
  for (int ex = 0; ex < E; ++ex) {
    unsigned long long m1 = __ballot(e.x == ex);
    if (m1) {
      int leader = __ffsll((long long)m1) - 1;
      int base = 0;
      if (lane == leader) base = atomicAdd(&meta[32 + ex], (int)__popcll(m1));
      base = __shfl(base, leader, 64);
      if (e.x == ex) {
        int pos = (int)__popcll(m1 & ((1ull << lane) - 1ull));
        int s1 = meta[16 + ex] + base + pos;
        LIST[s1] = t; WTS[s1] = w.x;
      }
    }
    unsigned long long m2 = __ballot(e.y == ex);
    if (m2) {
      int leader = __ffsll((long long)m2) - 1;
      int base = 0;
      if (lane == leader) base = atomicAdd(&meta[40 + ex], (int)__popcll(m2));
      base = __shfl(base, leader, 64);
      if (e.y == ex) {
        int pos = (int)__popcll(m2 & ((1ull << lane) - 1ull));
        int s2 = meta[24 + ex] + base + pos;
        LIST[s2] = t; WTS[s2] = w.y;
      }
    }
  }
}

// ---------------- weight convert + transpose: src [e][K][N] fp32 -> dst [e][N][K] bf16 ----
__global__ __launch_bounds__(256) void cvtw_kernel(const float* __restrict__ src,
                                                   unsigned short* __restrict__ dst,
                                                   int K, int N) {
  int e = blockIdx.x, k0 = blockIdx.y * 64, n0 = blockIdx.z * 64;
  src += (size_t)e * K * N;
  dst += (size_t)e * K * N;
  __shared__ float t[64][65];
  int tid = threadIdx.x;
  int tr = tid >> 4, tc = (tid & 15) * 4;
#pragma unroll
  for (int i = 0; i < 4; ++i) {
    int k = tr + i * 16;
    float4 v = *(const float4*)(src + (size_t)(k0 + k) * N + n0 + tc);
    t[k][tc] = v.x; t[k][tc + 1] = v.y; t[k][tc + 2] = v.z; t[k][tc + 3] = v.w;
  }
  __syncthreads();
  int n = tid >> 2, kk = (tid & 3) * 16;
  union { unsigned short u[16]; uint4 q[2]; } p;
#pragma unroll
  for (int j = 0; j < 16; ++j) p.u[j] = f2bf(t[kk + j][n]);
  uint4* o = (uint4*)(dst + (size_t)(n0 + n) * K + k0 + kk);
  o[0] = p.q[0]; o[1] = p.q[1];
}

// ---------------- GEMM1: Hc = relu(gather(X)*W1t[e]+b1[e]) --------
__global__ __launch_bounds__(256) void gemm1_kernel(
    const unsigned short* __restrict__ X,    // [TOK, D] bf16
    const unsigned short* __restrict__ w1t,  // [E, F, D] bf16 (n-major)
    const float* __restrict__ b1,            // [E, F]
    const int* __restrict__ LIST,            // [RTOT]
    const int* __restrict__ meta,
    unsigned short* __restrict__ Hc) {       // [RTOT, F] bf16
  const int K = D, N = F;
  int bx = blockIdx.x;
  int e = bx & 7;
  int t = bx >> 3;
  int n0 = (t & 15) * 128;   // n-fastest
  int m = t >> 4;            // 0..MT-1
  int cnt = meta[e] + meta[8 + e];
  int mrow = m * 128;
  if (mrow >= cnt) return;
  int rowStart = meta[16 + e] + mrow;
  int rowsLeft = cnt - mrow; if (rowsLeft > 128) rowsLeft = 128;

  __shared__ unsigned short As[128 * 32];  // [m][k] unpadded (glds layout)
  __shared__ unsigned short Bs[128 * 32];  // [n][k] unpadded (glds layout)
  int tid = threadIdx.x;
  int lane = tid & 63, wid = tid >> 6;
  int wm = (wid >> 1) * 64, wn = (wid & 1) * 64;
  int lr = lane & 15, lq = lane >> 4;

  int r0 = wid * 16 + (lane >> 2), r1 = 64 + r0;
  int kc = (lane & 3) * 8;
  int c0 = r0 < rowsLeft ? r0 : rowsLeft - 1;
  int c1 = r1 < rowsLeft ? r1 : rowsLeft - 1;
  const unsigned short* gA0 = X + (size_t)LIST[rowStart + c0] * K + kc;
  const unsigned short* gA1 = X + (size_t)LIST[rowStart + c1] * K + kc;
  const unsigned short* wb = w1t + (size_t)e * N * K;
  const unsigned short* gB0 = wb + (size_t)(n0 + r0) * K + kc;
  const unsigned short* gB1 = wb + (size_t)(n0 + r1) * K + kc;
  unsigned short* lA0 = &As[r0 * 32 + kc];
  unsigned short* lA1 = &As[r1 * 32 + kc];
  unsigned short* lB0 = &Bs[r0 * 32 + kc];
  unsigned short* lB1 = &Bs[r1 * 32 + kc];

  floatx4 acc[4][4];
#pragma unroll
  for (int i = 0; i < 4; ++i)
#pragma unroll
    for (int j = 0; j < 4; ++j) acc[i][j] = (floatx4){0.f, 0.f, 0.f, 0.f};

  for (int k0 = 0; k0 < K; k0 += 32) {
    __syncthreads();
    glds16(gA0 + k0, lA0);
    glds16(gA1 + k0, lA1);
    glds16(gB0 + k0, lB0);
    glds16(gB1 + k0, lB1);
    __syncthreads();
    short8 af[4], bfr[4];
#pragma unroll
    for (int i = 0; i < 4; ++i)
      af[i] = *(const short8*)&As[(wm + i * 16 + lr) * 32 + lq * 8];
#pragma unroll
    for (int j = 0; j < 4; ++j)
      bfr[j] = *(const short8*)&Bs[(wn + j * 16 + lr) * 32 + lq * 8];
#pragma unroll
    for (int i = 0; i < 4; ++i)
#pragma unroll
      for (int j = 0; j < 4; ++j)
        acc[i][j] = __builtin_amdgcn_mfma_f32_16x16x32_bf16(af[i], bfr[j], acc[i][j], 0, 0, 0);
  }
  const float* be = b1 + (size_t)e * N;
#pragma unroll
  for (int i = 0; i < 4; ++i) {
#pragma unroll
    for (int j = 0; j < 4; ++j) {
      int col = n0 + wn + j * 16 + lr;
      float bias = be[col];
#pragma unroll
      for (int r = 0; r < 4; ++r) {
        int row = wm + i * 16 + lq * 4 + r;
        if (row < rowsLeft) {
          float v = fmaxf(acc[i][j][r] + bias, 0.f);
          Hc[(size_t)(rowStart + row) * N + col] = f2bf(v);
        }
      }
    }
  }
}

// ---------------- GEMM2: out[tok] += w * (Hc*W2t[e] + b2[e]) ------
__global__ __launch_bounds__(256) void gemm2_kernel(
    const unsigned short* __restrict__ Hc,   // [RTOT, F] bf16
    const unsigned short* __restrict__ w2t,  // [E, D, F] bf16 (n-major)
    const float* __restrict__ b2,            // [E, D]
    const int* __restrict__ LIST, const float* __restrict__ WTS,
    const int* __restrict__ meta,
    float* __restrict__ out) {               // [TOK, D] fp32, pre-zeroed
  const int K = F, N = D;
  int bx = blockIdx.x;
  int e = bx & 7;
  int t = bx >> 3;
  int n0 = (t & 7) * 128;    // n-fastest
  int m = t >> 3;
  int cnt = meta[e] + meta[8 + e];
  int mrow = m * 128;
  if (mrow >= cnt) return;
  int rowStart = meta[16 + e] + mrow;
  int rowsLeft = cnt - mrow; if (rowsLeft > 128) rowsLeft = 128;

  __shared__ unsigned short As[128 * 32];
  __shared__ unsigned short Bs[128 * 32];
  int tid = threadIdx.x;
  int lane = tid & 63, wid = tid >> 6;
  int wm = (wid >> 1) * 64, wn = (wid & 1) * 64;
  int lr = lane & 15, lq = lane >> 4;

  int r0 = wid * 16 + (lane >> 2), r1 = 64 + r0;
  int kc = (lane & 3) * 8;
  int c0 = r0 < rowsLeft ? r0 : rowsLeft - 1;
  int c1 = r1 < rowsLeft ? r1 : rowsLeft - 1;
  const unsigned short* gA0 = Hc + (size_t)(rowStart + c0) * K + kc;
  const unsigned short* gA1 = Hc + (size_t)(rowStart + c1) * K + kc;
  const unsigned short* wb = w2t + (size_t)e * N * K;
  const unsigned short* gB0 = wb + (size_t)(n0 + r0) * K + kc;
  const unsigned short* gB1 = wb + (size_t)(n0 + r1) * K + kc;
  unsigned short* lA0 = &As[r0 * 32 + kc];
  unsigned short* lA1 = &As[r1 * 32 + kc];
  unsigned short* lB0 = &Bs[r0 * 32 + kc];
  unsigned short* lB1 = &Bs[r1 * 32 + kc];

  floatx4 acc[4][4];
#pragma unroll
  for (int i = 0; i < 4; ++i)
#pragma unroll
    for (int j = 0; j < 4; ++j) acc[i][j] = (floatx4){0.f, 0.f, 0.f, 0.f};

  for (int k0 = 0; k0 < K; k0 += 32) {
    __syncthreads();
    glds16(gA0 + k0, lA0);
    glds16(gA1 + k0, lA1);
    glds16(gB0 + k0, lB0);
    glds16(gB1 + k0, lB1);
    __syncthreads();
    short8 af[4], bfr[4];
#pragma unroll
    for (int i = 0; i < 4; ++i)
      af[i] = *(const short8*)&As[(wm + i * 16 + lr) * 32 + lq * 8];
#pragma unroll
    for (int j = 0; j < 4; ++j)
      bfr[j] = *(const short8*)&Bs[(wn + j * 16 + lr) * 32 + lq * 8];
#pragma unroll
    for (int i = 0; i < 4; ++i)
#pragma unroll
      for (int j = 0; j < 4; ++j)
        acc[i][j] = __builtin_amdgcn_mfma_f32_16x16x32_bf16(af[i], bfr[j], acc[i][j], 0, 0, 0);
  }
  const float* be = b2 + (size_t)e * N;
#pragma unroll
  for (int i = 0; i < 4; ++i) {
    int tokr[4]; float wtr[4]; bool val[4];
#pragma unroll
    for (int r = 0; r < 4; ++r) {
      int row = wm + i * 16 + lq * 4 + r;
      val[r] = row < rowsLeft;
      int gi = rowStart + (val[r] ? row : 0);
      tokr[r] = LIST[gi]; wtr[r] = WTS[gi];
    }
#pragma unroll
    for (int j = 0; j < 4; ++j) {
      int col = n0 + wn + j * 16 + lr;
      float bias = be[col];
#pragma unroll
      for (int r = 0; r < 4; ++r) {
        if (val[r]) {
          atomicAdd(&out[(size_t)tokr[r] * N + col], wtr[r] * (acc[i][j][r] + bias));
        }
      }
    }
  }
}

extern "C" void kernel_launch(void* const* d_in, const int* in_sizes, int n_in,
                              void* d_out, int out_size, void* d_ws, size_t ws_size,
                              hipStream_t stream) {
  (void)in_sizes; (void)n_in; (void)ws_size;
  const float* hs   = (const float*)d_in[0];
  const int*   mask = (const int*)d_in[1];
  const float* rw   = (const float*)d_in[2];
  const float* w1   = (const float*)d_in[3];
  const float* b1   = (const float*)d_in[4];
  const float* w2   = (const float*)d_in[5];
  const float* b2   = (const float*)d_in[6];
  float* out = (float*)d_out;

  char* ws = (char*)d_ws;
  int* meta  = (int*)ws;
  int2* te   = (int2*)(ws + 1024);
  float2* tw = (float2*)(ws + 1024 + (size_t)TOK * 8);
  int* LIST  = (int*)(ws + 1024 + (size_t)TOK * 16);
  float* WTS = (float*)(ws + 1024 + (size_t)TOK * 16 + (size_t)RTOT * 4);
  int* blkcnt = (int*)(ws + (512 << 10));                                         // 32 KB @ 512KB
  unsigned short* Xbf = (unsigned short*)(ws + (1 << 20));                        // 16 MB
  unsigned short* Hc  = (unsigned short*)(ws + (1 << 20) + (size_t)TOK * D * 2);  // 64 MB
  unsigned short* Wt  = (unsigned short*)(ws + (1 << 20) + (size_t)TOK * D * 2 +
                                          (size_t)RTOT * F * 2);                  // 32 MB (reused)

  hipMemsetAsync(meta, 0, 256, stream);
  hipMemsetAsync(out, 0, (size_t)out_size * sizeof(float), stream);
  router_kernel<<<RBLK, 256, 0, stream>>>(hs, mask, rw, te, tw, blkcnt, Xbf);
  prefix_kernel<<<1, 256, 0, stream>>>(blkcnt, meta);
  scatter_kernel<<<TOK / 256, 256, 0, stream>>>(te, tw, meta, LIST, WTS);
  // w1 [E][D][F] -> Wt [E][F][D] bf16
  cvtw_kernel<<<dim3(E, D / 64, F / 64), 256, 0, stream>>>(w1, Wt, D, F);
  gemm1_kernel<<<E * MT * (F / 128), 256, 0, stream>>>(Xbf, Wt, b1, LIST, meta, Hc);
  // w2 [E][F][D] -> Wt [E][D][F] bf16 (reuses the same buffer after gemm1)
  cvtw_kernel<<<dim3(E, F / 64, D / 64), 256, 0, stream>>>(w2, Wt, F, D);
  gemm2_kernel<<<E * MT * (D / 128), 256, 0, stream>>>(Hc, Wt, b2, LIST, WTS, meta, out);
}

// Round 2
// 450.175 us; speedup vs baseline: 1.5555x; 1.0678x over previous
//
#include <hip/hip_runtime.h>

typedef __attribute__((ext_vector_type(8))) short short8;
typedef __attribute__((ext_vector_type(4))) float floatx4;

static constexpr int D = 1024;
static constexpr int F = 2048;
static constexpr int E = 8;
static constexpr int TOK = 4 * 2048;   // 8192 tokens
static constexpr int RTOT = 2 * TOK;   // 16384 expert-rows total (top-2 exact)
static constexpr int MT = 24;          // m-tiles per expert (3072 rows >> mean 2048)
static constexpr int RBLK = 512;       // router blocks (16 tokens each)

__device__ __forceinline__ unsigned short f2bf(float f) {
  unsigned int u = __float_as_uint(f);
  unsigned int r = (u + 0x7fffu + ((u >> 16) & 1u)) >> 16;  // RNE
  return (unsigned short)r;
}

__device__ __forceinline__ void glds16(const unsigned short* g, unsigned short* l) {
  __builtin_amdgcn_global_load_lds(
      (const __attribute__((address_space(1))) void*)g,
      (__attribute__((address_space(3))) void*)l, 16, 0, 0);
}

// meta layout (ints): [0:8)=cntp  [8:16)=cnts  [16:24)=pbase  [24:32)=sbase
//                     [32:40)=curp [40:48)=curs
// ---------------- router (+ fused X fp32->bf16 convert) ----------------
__global__ __launch_bounds__(256) void router_kernel(
    const float* __restrict__ hs, const int* __restrict__ mask,
    const float* __restrict__ rw, int2* __restrict__ te, float2* __restrict__ tw,
    int* __restrict__ blkcnt, unsigned short* __restrict__ Xbf) {
  __shared__ float rwT[E][D];    // 32 KB, transposed [e][i]
  __shared__ int cnt[16];
  int tid = threadIdx.x;
  if (tid < 16) cnt[tid] = 0;
#pragma unroll
  for (int q = 0; q < 4; ++q) {
    int i = tid * 4 + q;
    float4 a = *(const float4*)(rw + (size_t)i * E);
    float4 b = *(const float4*)(rw + (size_t)i * E + 4);
    rwT[0][i] = a.x; rwT[1][i] = a.y; rwT[2][i] = a.z; rwT[3][i] = a.w;
    rwT[4][i] = b.x; rwT[5][i] = b.y; rwT[6][i] = b.z; rwT[7][i] = b.w;
  }
  __syncthreads();

  int lane = tid & 63, wid = tid >> 6;
  int tok0 = blockIdx.x * 16 + wid * 4;
#pragma unroll 1
  for (int tt = 0; tt < 4; ++tt) {
    int t = tok0 + tt;
    const float* x = hs + (size_t)t * D;
    float acc[E];
#pragma unroll
    for (int e = 0; e < E; ++e) acc[e] = 0.f;
#pragma unroll
    for (int j = 0; j < 4; ++j) {
      int i0 = j * 256 + lane * 4;
      float4 xv = *(const float4*)(x + i0);
      union { unsigned short u[4]; uint2 q; } p;
      p.u[0] = f2bf(xv.x); p.u[1] = f2bf(xv.y);
      p.u[2] = f2bf(xv.z); p.u[3] = f2bf(xv.w);
      *(uint2*)(Xbf + (size_t)t * D + i0) = p.q;
#pragma unroll
      for (int e = 0; e < E; ++e) {
        float4 rv = *(const float4*)&rwT[e][i0];
        acc[e] += xv.x * rv.x + xv.y * rv.y + xv.z * rv.z + xv.w * rv.w;
      }
    }
#pragma unroll
    for (int off = 32; off > 0; off >>= 1) {
#pragma unroll
      for (int e = 0; e < E; ++e) acc[e] += __shfl_xor(acc[e], off, 64);
    }
    if (lane == 0) {
      int i1 = 0;
#pragma unroll
      for (int e = 1; e < E; ++e) if (acc[e] > acc[i1]) i1 = e;  // lowest argmax (jax tie rule)
      int i2 = (i1 == 0) ? 1 : 0;
#pragma unroll
      for (int e = 0; e < E; ++e) if (e != i1 && acc[e] > acc[i2]) i2 = e;
      float mx = fmaxf(acc[i1], acc[i2]);
      float e1 = expf(acc[i1] - mx), e2 = expf(acc[i2] - mx);
      float s = e1 + e2;
      float m = (mask[t] != 0) ? 1.f : 0.f;
      te[t] = make_int2(i1, i2);
      tw[t] = make_float2(e1 / s * m, e2 / s * m);
      atomicAdd(&cnt[i1], 1);
      atomicAdd(&cnt[8 + i2], 1);
    }
  }
  __syncthreads();
  if (tid < 16) blkcnt[blockIdx.x * 16 + tid] = cnt[tid];
}

// ---------------- prefix: sum per-block histograms + exclusive scan ----------------
__global__ __launch_bounds__(256) void prefix_kernel(const int* __restrict__ blkcnt,
                                                     int* __restrict__ meta) {
  __shared__ int part[256];
  int tid = threadIdx.x;
  int c = tid & 15, g = tid >> 4;
  int s = 0;
  for (int b = g; b < RBLK; b += 16) s += blkcnt[b * 16 + c];
  part[tid] = s;
  __syncthreads();
  if (tid < 16) {
    int tot = 0;
#pragma unroll
    for (int g2 = 0; g2 < 16; ++g2) tot += part[g2 * 16 + tid];
    meta[tid] = tot;
  }
  __syncthreads();
  if (tid == 0) {
    int run = 0;
    for (int e = 0; e < E; ++e) {
      meta[16 + e] = run;                 // pbase
      meta[24 + e] = run + meta[e];       // sbase
      run += meta[e] + meta[8 + e];
    }
  }
}

// ---------------- scatter: build LIST/WTS + inverse slot maps ----------------
__global__ __launch_bounds__(256) void scatter_kernel(
    const int2* __restrict__ te, const float2* __restrict__ tw,
    int* __restrict__ meta, int* __restrict__ LIST, float* __restrict__ WTS,
    int* __restrict__ slotp, int* __restrict__ slots) {
  int t = blockIdx.x * 256 + threadIdx.x;
  int lane = threadIdx.x & 63;
  int2 e = te[t];
  float2 w = tw[t];
#pragma unroll
  for (int ex = 0; ex < E; ++ex) {
    unsigned long long m1 = __ballot(e.x == ex);
    if (m1) {
      int leader = __ffsll((long long)m1) - 1;
      int base = 0;
      if (lane == leader) base = atomicAdd(&meta[32 + ex], (int)__popcll(m1));
      base = __shfl(base, leader, 64);
      if (e.x == ex) {
        int pos = (int)__popcll(m1 & ((1ull << lane) - 1ull));
        int s1 = meta[16 + ex] + base + pos;
        LIST[s1] = t; WTS[s1] = w.x; slotp[t] = s1;
      }
    }
    unsigned long long m2 = __ballot(e.y == ex);
    if (m2) {
      int leader = __ffsll((long long)m2) - 1;
      int base = 0;
      if (lane == leader) base = atomicAdd(&meta[40 + ex], (int)__popcll(m2));
      base = __shfl(base, leader, 64);
      if (e.y == ex) {
        int pos = (int)__popcll(m2 & ((1ull << lane) - 1ull));
        int s2 = meta[24 + ex] + base + pos;
        LIST[s2] = t; WTS[s2] = w.y; slots[t] = s2;
      }
    }
  }
}

// ---------------- weight convert + transpose: src [e][K][N] fp32 -> dst [e][N][K] bf16 ----
__global__ __launch_bounds__(256) void cvtw_kernel(const float* __restrict__ src,
                                                   unsigned short* __restrict__ dst,
                                                   int K, int N) {
  int e = blockIdx.x, k0 = blockIdx.y * 64, n0 = blockIdx.z * 64;
  src += (size_t)e * K * N;
  dst += (size_t)e * K * N;
  __shared__ float t[64][65];
  int tid = threadIdx.x;
  int tr = tid >> 4, tc = (tid & 15) * 4;
#pragma unroll
  for (int i = 0; i < 4; ++i) {
    int k = tr + i * 16;
    float4 v = *(const float4*)(src + (size_t)(k0 + k) * N + n0 + tc);
    t[k][tc] = v.x; t[k][tc + 1] = v.y; t[k][tc + 2] = v.z; t[k][tc + 3] = v.w;
  }
  __syncthreads();
  int n = tid >> 2, kk = (tid & 3) * 16;
  union { unsigned short u[16]; uint4 q[2]; } p;
#pragma unroll
  for (int j = 0; j < 16; ++j) p.u[j] = f2bf(t[kk + j][n]);
  uint4* o = (uint4*)(dst + (size_t)(n0 + n) * K + k0 + kk);
  o[0] = p.q[0]; o[1] = p.q[1];
}

// ---------------- GEMM1: Hc = relu(gather(X)*W1t[e]+b1[e]) --------
__global__ __launch_bounds__(256) void gemm1_kernel(
    const unsigned short* __restrict__ X,    // [TOK, D] bf16
    const unsigned short* __restrict__ w1t,  // [E, F, D] bf16 (n-major)
    const float* __restrict__ b1,            // [E, F]
    const int* __restrict__ LIST,            // [RTOT]
    const int* __restrict__ meta,
    unsigned short* __restrict__ Hc) {       // [RTOT, F] bf16
  const int K = D, N = F;
  int bx = blockIdx.x;
  int e = bx & 7;
  int t = bx >> 3;
  int n0 = (t & 15) * 128;   // n-fastest
  int m = t >> 4;            // 0..MT-1
  int cnt = meta[e] + meta[8 + e];
  int mrow = m * 128;
  if (mrow >= cnt) return;
  int rowStart = meta[16 + e] + mrow;
  int rowsLeft = cnt - mrow; if (rowsLeft > 128) rowsLeft = 128;

  __shared__ unsigned short As[128 * 32];  // [m][k] unpadded (glds layout)
  __shared__ unsigned short Bs[128 * 32];  // [n][k] unpadded (glds layout)
  int tid = threadIdx.x;
  int lane = tid & 63, wid = tid >> 6;
  int wm = (wid >> 1) * 64, wn = (wid & 1) * 64;
  int lr = lane & 15, lq = lane >> 4;

  int r0 = wid * 16 + (lane >> 2), r1 = 64 + r0;
  int kc = (lane & 3) * 8;
  int c0 = r0 < rowsLeft ? r0 : rowsLeft - 1;
  int c1 = r1 < rowsLeft ? r1 : rowsLeft - 1;
  const unsigned short* gA0 = X + (size_t)LIST[rowStart + c0] * K + kc;
  const unsigned short* gA1 = X + (size_t)LIST[rowStart + c1] * K + kc;
  const unsigned short* wb = w1t + (size_t)e * N * K;
  const unsigned short* gB0 = wb + (size_t)(n0 + r0) * K + kc;
  const unsigned short* gB1 = wb + (size_t)(n0 + r1) * K + kc;
  unsigned short* lA0 = &As[r0 * 32 + kc];
  unsigned short* lA1 = &As[r1 * 32 + kc];
  unsigned short* lB0 = &Bs[r0 * 32 + kc];
  unsigned short* lB1 = &Bs[r1 * 32 + kc];

  floatx4 acc[4][4];
#pragma unroll
  for (int i = 0; i < 4; ++i)
#pragma unroll
    for (int j = 0; j < 4; ++j) acc[i][j] = (floatx4){0.f, 0.f, 0.f, 0.f};

  for (int k0 = 0; k0 < K; k0 += 32) {
    __syncthreads();
    glds16(gA0 + k0, lA0);
    glds16(gA1 + k0, lA1);
    glds16(gB0 + k0, lB0);
    glds16(gB1 + k0, lB1);
    __syncthreads();
    short8 af[4], bfr[4];
#pragma unroll
    for (int i = 0; i < 4; ++i)
      af[i] = *(const short8*)&As[(wm + i * 16 + lr) * 32 + lq * 8];
#pragma unroll
    for (int j = 0; j < 4; ++j)
      bfr[j] = *(const short8*)&Bs[(wn + j * 16 + lr) * 32 + lq * 8];
#pragma unroll
    for (int i = 0; i < 4; ++i)
#pragma unroll
      for (int j = 0; j < 4; ++j)
        acc[i][j] = __builtin_amdgcn_mfma_f32_16x16x32_bf16(af[i], bfr[j], acc[i][j], 0, 0, 0);
  }
  const float* be = b1 + (size_t)e * N;
#pragma unroll
  for (int i = 0; i < 4; ++i) {
#pragma unroll
    for (int j = 0; j < 4; ++j) {
      int col = n0 + wn + j * 16 + lr;
      float bias = be[col];
#pragma unroll
      for (int r = 0; r < 4; ++r) {
        int row = wm + i * 16 + lq * 4 + r;
        if (row < rowsLeft) {
          float v = fmaxf(acc[i][j][r] + bias, 0.f);
          Hc[(size_t)(rowStart + row) * N + col] = f2bf(v);
        }
      }
    }
  }
}

// ---------------- GEMM2: Yc[slot] = w*(Hc*W2t[e]+b2[e])  (MODE1, no atomics)
//                  or    out[tok] += ...                   (MODE0 fallback)
template <int MODE>
__global__ __launch_bounds__(256) void gemm2_kernel(
    const unsigned short* __restrict__ Hc,   // [RTOT, F] bf16
    const unsigned short* __restrict__ w2t,  // [E, D, F] bf16 (n-major)
    const float* __restrict__ b2,            // [E, D]
    const int* __restrict__ LIST, const float* __restrict__ WTS,
    const int* __restrict__ meta,
    float* __restrict__ out,                 // [TOK, D] fp32 (MODE0: pre-zeroed)
    float* __restrict__ Yc) {                // [RTOT, D] fp32 (MODE1)
  const int K = F, N = D;
  int bx = blockIdx.x;
  int e = bx & 7;
  int t = bx >> 3;
  int n0 = (t & 7) * 128;    // n-fastest
  int m = t >> 3;
  int cnt = meta[e] + meta[8 + e];
  int mrow = m * 128;
  if (mrow >= cnt) return;
  int rowStart = meta[16 + e] + mrow;
  int rowsLeft = cnt - mrow; if (rowsLeft > 128) rowsLeft = 128;

  __shared__ unsigned short As[128 * 32];
  __shared__ unsigned short Bs[128 * 32];
  int tid = threadIdx.x;
  int lane = tid & 63, wid = tid >> 6;
  int wm = (wid >> 1) * 64, wn = (wid & 1) * 64;
  int lr = lane & 15, lq = lane >> 4;

  int r0 = wid * 16 + (lane >> 2), r1 = 64 + r0;
  int kc = (lane & 3) * 8;
  int c0 = r0 < rowsLeft ? r0 : rowsLeft - 1;
  int c1 = r1 < rowsLeft ? r1 : rowsLeft - 1;
  const unsigned short* gA0 = Hc + (size_t)(rowStart + c0) * K + kc;
  const unsigned short* gA1 = Hc + (size_t)(rowStart + c1) * K + kc;
  const unsigned short* wb = w2t + (size_t)e * N * K;
  const unsigned short* gB0 = wb + (size_t)(n0 + r0) * K + kc;
  const unsigned short* gB1 = wb + (size_t)(n0 + r1) * K + kc;
  unsigned short* lA0 = &As[r0 * 32 + kc];
  unsigned short* lA1 = &As[r1 * 32 + kc];
  unsigned short* lB0 = &Bs[r0 * 32 + kc];
  unsigned short* lB1 = &Bs[r1 * 32 + kc];

  floatx4 acc[4][4];
#pragma unroll
  for (int i = 0; i < 4; ++i)
#pragma unroll
    for (int j = 0; j < 4; ++j) acc[i][j] = (floatx4){0.f, 0.f, 0.f, 0.f};

  for (int k0 = 0; k0 < K; k0 += 32) {
    __syncthreads();
    glds16(gA0 + k0, lA0);
    glds16(gA1 + k0, lA1);
    glds16(gB0 + k0, lB0);
    glds16(gB1 + k0, lB1);
    __syncthreads();
    short8 af[4], bfr[4];
#pragma unroll
    for (int i = 0; i < 4; ++i)
      af[i] = *(const short8*)&As[(wm + i * 16 + lr) * 32 + lq * 8];
#pragma unroll
    for (int j = 0; j < 4; ++j)
      bfr[j] = *(const short8*)&Bs[(wn + j * 16 + lr) * 32 + lq * 8];
#pragma unroll
    for (int i = 0; i < 4; ++i)
#pragma unroll
      for (int j = 0; j < 4; ++j)
        acc[i][j] = __builtin_amdgcn_mfma_f32_16x16x32_bf16(af[i], bfr[j], acc[i][j], 0, 0, 0);
  }
  const float* be = b2 + (size_t)e * N;
#pragma unroll
  for (int i = 0; i < 4; ++i) {
    int tokr[4]; float wtr[4]; bool val[4];
#pragma unroll
    for (int r = 0; r < 4; ++r) {
      int row = wm + i * 16 + lq * 4 + r;
      val[r] = row < rowsLeft;
      int gi = rowStart + (val[r] ? row : 0);
      if (MODE == 0) tokr[r] = LIST[gi];
      wtr[r] = WTS[gi];
    }
#pragma unroll
    for (int j = 0; j < 4; ++j) {
      int col = n0 + wn + j * 16 + lr;
      float bias = be[col];
#pragma unroll
      for (int r = 0; r < 4; ++r) {
        if (val[r]) {
          float v = wtr[r] * (acc[i][j][r] + bias);
          if (MODE == 0) {
            atomicAdd(&out[(size_t)tokr[r] * N + col], v);
          } else {
            int row = wm + i * 16 + lq * 4 + r;
            Yc[(size_t)(rowStart + row) * N + col] = v;
          }
        }
      }
    }
  }
}

// ---------------- combine: out[t] = Yc[slotp[t]] + Yc[slots[t]] ----------------
__global__ __launch_bounds__(256) void combine_kernel(
    const float* __restrict__ Yc, const int* __restrict__ slotp,
    const int* __restrict__ slots, float* __restrict__ out) {
  int t = blockIdx.x;              // one token per block, 256 float4 = 1024 floats
  int d4 = threadIdx.x * 4;
  int s1 = slotp[t], s2 = slots[t];
  float4 a = *(const float4*)(Yc + (size_t)s1 * D + d4);
  float4 b = *(const float4*)(Yc + (size_t)s2 * D + d4);
  float4 o;
  o.x = a.x + b.x; o.y = a.y + b.y; o.z = a.z + b.z; o.w = a.w + b.w;
  *(float4*)(out + (size_t)t * D + d4) = o;
}

extern "C" void kernel_launch(void* const* d_in, const int* in_sizes, int n_in,
                              void* d_out, int out_size, void* d_ws, size_t ws_size,
                              hipStream_t stream) {
  (void)in_sizes; (void)n_in;
  const float* hs   = (const float*)d_in[0];
  const int*   mask = (const int*)d_in[1];
  const float* rw   = (const float*)d_in[2];
  const float* w1   = (const float*)d_in[3];
  const float* b1   = (const float*)d_in[4];
  const float* w2   = (const float*)d_in[5];
  const float* b2   = (const float*)d_in[6];
  float* out = (float*)d_out;

  char* ws = (char*)d_ws;
  int* meta  = (int*)ws;
  int2* te   = (int2*)(ws + 1024);
  float2* tw = (float2*)(ws + 1024 + (size_t)TOK * 8);
  int* LIST  = (int*)(ws + 1024 + (size_t)TOK * 16);
  float* WTS = (float*)(ws + 1024 + (size_t)TOK * 16 + (size_t)RTOT * 4);
  int* slotp = (int*)(ws + 1024 + (size_t)TOK * 16 + (size_t)RTOT * 8);
  int* slots = (int*)(ws + 1024 + (size_t)TOK * 16 + (size_t)RTOT * 8 + (size_t)TOK * 4);
  int* blkcnt = (int*)(ws + (512 << 10));                                         // 32 KB @ 512KB
  unsigned short* Xbf = (unsigned short*)(ws + (1 << 20));                        // 16 MB
  unsigned short* Hc  = (unsigned short*)(ws + (1 << 20) + (size_t)TOK * D * 2);  // 64 MB
  unsigned short* Wt  = (unsigned short*)(ws + (1 << 20) + (size_t)TOK * D * 2 +
                                          (size_t)RTOT * F * 2);                  // 32 MB (reused)
  size_t yc_off = (size_t)(1 << 20) + (size_t)TOK * D * 2 + (size_t)RTOT * F * 2 +
                  (size_t)E * (size_t)D * F * 2;
  float* Yc = (float*)(ws + yc_off);                                              // 64 MB
  bool wide = ws_size >= yc_off + (size_t)RTOT * D * 4;

  hipMemsetAsync(meta, 0, 256, stream);
  if (!wide) hipMemsetAsync(out, 0, (size_t)out_size * sizeof(float), stream);
  router_kernel<<<RBLK, 256, 0, stream>>>(hs, mask, rw, te, tw, blkcnt, Xbf);
  prefix_kernel<<<1, 256, 0, stream>>>(blkcnt, meta);
  scatter_kernel<<<TOK / 256, 256, 0, stream>>>(te, tw, meta, LIST, WTS, slotp, slots);
  // w1 [E][D][F] -> Wt [E][F][D] bf16
  cvtw_kernel<<<dim3(E, D / 64, F / 64), 256, 0, stream>>>(w1, Wt, D, F);
  gemm1_kernel<<<E * MT * (F / 128), 256, 0, stream>>>(Xbf, Wt, b1, LIST, meta, Hc);
  // w2 [E][F][D] -> Wt [E][D][F] bf16 (reuses the same buffer after gemm1)
  cvtw_kernel<<<dim3(E, F / 64, D / 64), 256, 0, stream>>>(w2, Wt, F, D);
  if (wide) {
    gemm2_kernel<1><<<E * MT * (D / 128), 256, 0, stream>>>(Hc, Wt, b2, LIST, WTS, meta, out, Yc);
    combine_kernel<<<TOK, 256, 0, stream>>>(Yc, slotp, slots, out);
  } else {
    gemm2_kernel<0><<<E * MT * (D / 128), 256, 0, stream>>>(Hc, Wt, b2, LIST, WTS, meta, out, Yc);
  }
}